// Round 18
// baseline (451.291 us; speedup 1.0000x reference)
//
#include <hip/hip_runtime.h>
#include <hip/hip_bf16.h>
#include <math.h>

#define N_NODES 50000
#define N_EDGES 400000
#define HID 128
#define NH 8
#define HS 16
#define TN 8
#define NR 8
#define TILE 32
#define MAXTILES 1571
#define PERM_SZ (MAXTILES * TILE)
#define SCAN_BLKS ((N_NODES + 255) / 256)   // 196
#define NB 3125                              // dst windows of 16 nodes (exact)
#define TPBMAX 26                            // max 16-edge tiles per window
#define CAP 240                              // max edges per window (~10 sigma)
#define MPITCH 68                            // smg row pitch in shorts
#define SPITCH 5                             // ssc row pitch in floats

typedef __attribute__((ext_vector_type(8))) short bf16x8;
typedef __attribute__((ext_vector_type(4))) float f32x4;

__device__ __forceinline__ unsigned short f2bf(float f) {
    __hip_bfloat16 h = __float2bfloat16(f);
    return *reinterpret_cast<unsigned short*>(&h);
}
__device__ __forceinline__ float bf2f(unsigned short u) {
    return __uint_as_float((unsigned)u << 16);
}

// ---------- node type sort (LDS-aggregated counting sort) ----------
__global__ void hist_kernel(const int* __restrict__ ntype, int* __restrict__ cnt) {
    __shared__ int l[TN];
    if (threadIdx.x < TN) l[threadIdx.x] = 0;
    __syncthreads();
    int i = blockIdx.x * 256 + threadIdx.x;
    if (i < N_NODES) atomicAdd(&l[ntype[i]], 1);
    __syncthreads();
    if (threadIdx.x < TN) atomicAdd(&cnt[threadIdx.x], l[threadIdx.x]);
}
__global__ void scan_kernel(const int* __restrict__ cnt, int* __restrict__ cursor) {
    if (threadIdx.x == 0 && blockIdx.x == 0) {
        int acc = 0;
        for (int t = 0; t < TN; ++t) {
            cursor[t] = acc;
            acc += ((cnt[t] + TILE - 1) / TILE) * TILE;
        }
    }
}
__global__ void scatter_kernel(const int* __restrict__ ntype, int* __restrict__ cursor,
                               int* __restrict__ perm) {
    __shared__ int lcnt[TN], lbase[TN];
    if (threadIdx.x < TN) lcnt[threadIdx.x] = 0;
    __syncthreads();
    int i = blockIdx.x * 256 + threadIdx.x;
    int t = 0, off = 0;
    if (i < N_NODES) {
        t = ntype[i];
        off = atomicAdd(&lcnt[t], 1);
    }
    __syncthreads();
    if (threadIdx.x < TN)
        lbase[threadIdx.x] = atomicAdd(&cursor[threadIdx.x], lcnt[threadIdx.x]);
    __syncthreads();
    if (i < N_NODES) perm[lbase[t] + off] = i;
}

// ---------- edge CSR build (sort by dst) ----------
__global__ void hist_dst_kernel(const int* __restrict__ dst, int* __restrict__ cnt) {
    int e = blockIdx.x * 256 + threadIdx.x;
    if (e < N_EDGES) atomicAdd(&cnt[dst[e]], 1);
}
__global__ void scan_block_kernel(const int* __restrict__ cnt, int* __restrict__ excl,
                                  int* __restrict__ bsum) {
    __shared__ int s[256];
    int tid = threadIdx.x;
    int i = blockIdx.x * 256 + tid;
    int v = (i < N_NODES) ? cnt[i] : 0;
    s[tid] = v;
    __syncthreads();
    for (int off = 1; off < 256; off <<= 1) {
        int t = (tid >= off) ? s[tid - off] : 0;
        __syncthreads();
        s[tid] += t;
        __syncthreads();
    }
    if (i < N_NODES) excl[i] = s[tid] - v;
    if (tid == 255) bsum[blockIdx.x] = s[255];
}
__global__ void scan_top_kernel(int* __restrict__ bsum) {
    __shared__ int s[256];
    int tid = threadIdx.x;
    int v = (tid < SCAN_BLKS) ? bsum[tid] : 0;
    s[tid] = v;
    __syncthreads();
    for (int off = 1; off < 256; off <<= 1) {
        int t = (tid >= off) ? s[tid - off] : 0;
        __syncthreads();
        s[tid] += t;
        __syncthreads();
    }
    if (tid < SCAN_BLKS) bsum[tid] = s[tid] - v;   // exclusive
}
__global__ void scan_add_kernel(int* __restrict__ excl, const int* __restrict__ bsum,
                                int* __restrict__ cursor) {
    int i = blockIdx.x * 256 + threadIdx.x;
    if (i < N_NODES) {
        int v = excl[i] + bsum[blockIdx.x];
        excl[i] = v;        // becomes row_ptr
        cursor[i] = v;
    }
}
// place edges at CSR positions (by dst)
__global__ void csr_scatter_kernel(const int* __restrict__ src, const int* __restrict__ dst,
                                   const int* __restrict__ etype, int* __restrict__ cur_dst,
                                   int* __restrict__ csr_sd, int* __restrict__ csr_et) {
    int e = blockIdx.x * 256 + threadIdx.x;
    if (e < N_EDGES) {
        int p = atomicAdd(&cur_dst[dst[e]], 1);
        csr_sd[p] = src[e] | (dst[e] << 16);
        csr_et[p] = etype[e];
    }
}

// ---------- per-window relation tile build (once) ----------
__global__ void btile_build(const int* __restrict__ row_ptr,
                            const int* __restrict__ csr_sd, const int* __restrict__ csr_et,
                            int* __restrict__ btile_sd, int* __restrict__ btile_lp,
                            int* __restrict__ btile_r, int* __restrict__ ntb) {
    int b = blockIdx.x;
    int lane = threadIdx.x;              // 64 threads = 1 wave
    int p0 = row_ptr[b * 16];
    int p1 = (b == NB - 1) ? N_EDGES : row_ptr[b * 16 + 16];
    int cnt = 0;
    if (lane < 8) {
        for (int p = p0; p < p1; ++p) cnt += (csr_et[p] == lane);
    }
    int tiles = (cnt + 15) >> 4;
    int pre = 0, total = 0;
    for (int k = 0; k < 8; ++k) {
        int tk = __shfl(tiles, k);
        if (k < lane) pre += tk;
        total += tk;
    }
    if (lane == 0) ntb[b] = total;
    if (lane < 8) {
        int tbase = b * TPBMAX + pre;
        for (int t = 0; t < tiles; ++t) btile_r[tbase + t] = lane;
        int off = 0;
        for (int p = p0; p < p1; ++p) {
            if (csr_et[p] == lane) {
                int idx = (tbase + (off >> 4)) * 16 + (off & 15);
                btile_sd[idx] = csr_sd[p];
                btile_lp[idx] = p - p0;
                ++off;
            }
        }
        for (; off < tiles * 16; ++off) {
            int idx = (tbase + (off >> 4)) * 16 + (off & 15);
            btile_sd[idx] = 0;
            btile_lp[idx] = CAP;         // scratch slot
        }
    }
}

// ---------- weight converts ----------
__global__ void wconv_all_kernel(const float* __restrict__ Wk, const float* __restrict__ Wq,
                                 const float* __restrict__ Wv, const float* __restrict__ Wa,
                                 const float* __restrict__ Wff,
                                 unsigned short* __restrict__ WkT, unsigned short* __restrict__ WqT,
                                 unsigned short* __restrict__ WvT, unsigned short* __restrict__ WaT,
                                 unsigned short* __restrict__ WffT) {
    int blk = blockIdx.x;                 // [0, 65*8)
    int m16 = blk >> 3;                   // 0..64 ; 64 => Wff
    int seg = blk & 7;
    const float* w;
    unsigned short* o;
    if (m16 < 64) {
        int grp = m16 >> 4, mat = m16 & 15;
        const float* Wsrc = grp == 0 ? Wk : (grp == 1 ? Wq : (grp == 2 ? Wv : Wa));
        unsigned short* Wdst = grp == 0 ? WkT : (grp == 1 ? WqT : (grp == 2 ? WvT : WaT));
        w = Wsrc + (size_t)mat * HID * HID;
        o = Wdst + (size_t)mat * HID * HID;
    } else {
        w = Wff;
        o = WffT;
    }
#pragma unroll
    for (int c = 0; c < 8; ++c) {
        int idx = seg * 2048 + c * 256 + threadIdx.x;
        int i = idx >> 7, j = idx & 127;
        o[j * HID + i] = f2bf(w[idx]);
    }
}
__global__ void wsmall_conv(const float* __restrict__ W, const float* __restrict__ pri,
                            unsigned short* __restrict__ out) {
    int blk = blockIdx.x;                 // l*64 + h*8 + r
    int tid = threadIdx.x;                // 256 = 16x16
    int i = tid >> 4, o = tid & 15;
    float s = pri ? pri[blk] * 0.25f : 1.f;
    out[blk * 256 + o * 16 + i] = f2bf(W[blk * 256 + i * 16 + o] * s);
}

// ---------- MFMA typed GEMM: 32 nodes x 128 outs; K,Q,V all bf16 ----------
__global__ __launch_bounds__(256) void gemm3_mfma(
    const float* __restrict__ x, const int* __restrict__ perm, const int* __restrict__ ntype,
    const unsigned short* __restrict__ WkT, const unsigned short* __restrict__ WqT,
    const unsigned short* __restrict__ WvT,
    unsigned short* __restrict__ Kb, unsigned short* __restrict__ Qb,
    unsigned short* __restrict__ Vb) {
    __shared__ unsigned short xs[TILE][HID + 8];
    __shared__ int nodes[TILE];
    int tid = threadIdx.x;
    if (tid < TILE) nodes[tid] = perm[blockIdx.x * TILE + tid];
    __syncthreads();
    if (nodes[0] < 0) return;
    int t = ntype[nodes[0]];
#pragma unroll
    for (int c = 0; c < 4; ++c) {
        int v = tid + c * 256;
        int ns = v >> 5, ii = (v & 31) * 4;
        int node = nodes[ns];
        float4 val = (node >= 0) ? *(const float4*)(x + (size_t)node * HID + ii)
                                 : make_float4(0.f, 0.f, 0.f, 0.f);
        uint2 pk;
        pk.x = (unsigned)f2bf(val.x) | ((unsigned)f2bf(val.y) << 16);
        pk.y = (unsigned)f2bf(val.z) | ((unsigned)f2bf(val.w) << 16);
        *(uint2*)&xs[ns][ii] = pk;
    }
    __syncthreads();
    int wv = tid >> 6, lane = tid & 63;
    int lrow = lane & 15, lk = lane >> 4;
    bf16x8 af[2][4];
#pragma unroll
    for (int rt = 0; rt < 2; ++rt)
#pragma unroll
        for (int kk = 0; kk < 4; ++kk)
            af[rt][kk] = *(const bf16x8*)&xs[rt * 16 + lrow][kk * 32 + lk * 8];
    size_t woff = (size_t)t * HID * HID + (size_t)lrow * HID + lk * 8;
#pragma unroll
    for (int pp = 0; pp < 6; ++pp) {
        int p = wv * 6 + pp;
        int mat = p >> 3, ct = p & 7;
        const unsigned short* wb =
            (mat == 0 ? WkT : (mat == 1 ? WqT : WvT)) + woff + (size_t)ct * 16 * HID;
        unsigned short* ob = (mat == 0) ? Kb : (mat == 1 ? Qb : Vb);
        f32x4 a0 = {0.f, 0.f, 0.f, 0.f}, a1 = {0.f, 0.f, 0.f, 0.f};
#pragma unroll
        for (int kk = 0; kk < 4; ++kk) {
            bf16x8 bfr = *(const bf16x8*)(wb + kk * 32);
            a0 = __builtin_amdgcn_mfma_f32_16x16x32_bf16(af[0][kk], bfr, a0, 0, 0, 0);
            a1 = __builtin_amdgcn_mfma_f32_16x16x32_bf16(af[1][kk], bfr, a1, 0, 0, 0);
        }
        int col = ct * 16 + lrow;
#pragma unroll
        for (int q = 0; q < 4; ++q) {
            int r0 = lk * 4 + q;
            int n0 = nodes[r0], n1 = nodes[16 + r0];
            if (n0 >= 0) ob[(size_t)n0 * HID + col] = f2bf(a0[q]);
            if (n1 >= 0) ob[(size_t)n1 * HID + col] = f2bf(a1[q]);
        }
    }
}

// ---------- MFMA GEMM (plain, fp32 in, fp32 out, +bias) for final FF ----------
__global__ __launch_bounds__(256) void gemm1_mfma(
    const float* __restrict__ x, const int* __restrict__ perm, const int* __restrict__ ntype,
    const unsigned short* __restrict__ Wt, const float* __restrict__ bias,
    float* __restrict__ out) {
    __shared__ unsigned short xs[TILE][HID + 8];
    __shared__ int nodes[TILE];
    int tid = threadIdx.x;
    if (tid < TILE) {
        int n;
        if (perm) n = perm[blockIdx.x * TILE + tid];
        else { n = blockIdx.x * TILE + tid; if (n >= N_NODES) n = -1; }
        nodes[tid] = n;
    }
    __syncthreads();
    if (nodes[0] < 0) return;
    int t = perm ? ntype[nodes[0]] : 0;
#pragma unroll
    for (int c = 0; c < 4; ++c) {
        int v = tid + c * 256;
        int ns = v >> 5, ii = (v & 31) * 4;
        int node = nodes[ns];
        float4 val = (node >= 0) ? *(const float4*)(x + (size_t)node * HID + ii)
                                 : make_float4(0.f, 0.f, 0.f, 0.f);
        uint2 pk;
        pk.x = (unsigned)f2bf(val.x) | ((unsigned)f2bf(val.y) << 16);
        pk.y = (unsigned)f2bf(val.z) | ((unsigned)f2bf(val.w) << 16);
        *(uint2*)&xs[ns][ii] = pk;
    }
    __syncthreads();
    int wv = tid >> 6, lane = tid & 63;
    int lrow = lane & 15, lk = lane >> 4;
    bf16x8 af[2][4];
#pragma unroll
    for (int rt = 0; rt < 2; ++rt)
#pragma unroll
        for (int kk = 0; kk < 4; ++kk)
            af[rt][kk] = *(const bf16x8*)&xs[rt * 16 + lrow][kk * 32 + lk * 8];
    const unsigned short* wb0 = Wt + (size_t)t * HID * HID + (size_t)lrow * HID + lk * 8;
#pragma unroll
    for (int pp = 0; pp < 2; ++pp) {
        int ct = wv * 2 + pp;
        const unsigned short* wb = wb0 + (size_t)ct * 16 * HID;
        f32x4 a0 = {0.f, 0.f, 0.f, 0.f}, a1 = {0.f, 0.f, 0.f, 0.f};
#pragma unroll
        for (int kk = 0; kk < 4; ++kk) {
            bf16x8 bfr = *(const bf16x8*)(wb + kk * 32);
            a0 = __builtin_amdgcn_mfma_f32_16x16x32_bf16(af[0][kk], bfr, a0, 0, 0, 0);
            a1 = __builtin_amdgcn_mfma_f32_16x16x32_bf16(af[1][kk], bfr, a1, 0, 0, 0);
        }
        float bv = bias ? bias[ct * 16 + lrow] : 0.f;
#pragma unroll
        for (int q = 0; q < 4; ++q) {
            int r0 = lk * 4 + q;
            int n0 = nodes[r0], n1 = nodes[16 + r0];
            if (n0 >= 0) out[(size_t)n0 * HID + ct * 16 + lrow] = a0[q] + bv;
            if (n1 >= 0) out[(size_t)n1 * HID + ct * 16 + lrow] = a1[q] + bv;
        }
    }
}

// ---------- MFMA typed GEMM (bf16 agg in) + SiLU + gated residual + LayerNorm ----------
__global__ __launch_bounds__(256) void gemm1_ln_mfma(
    const unsigned short* __restrict__ aggb, const int* __restrict__ perm,
    const int* __restrict__ ntype, const unsigned short* __restrict__ Wt,
    const float* __restrict__ xin, const float* __restrict__ skip,
    const float* __restrict__ g, const float* __restrict__ b, float* __restrict__ xout) {
    __shared__ unsigned short xs[TILE][HID + 8];
    __shared__ int nodes[TILE];
    __shared__ float psum[TILE][4], psq[TILE][4];
    __shared__ float mu_s[TILE], rv_s[TILE];
    int tid = threadIdx.x;
    if (tid < TILE) nodes[tid] = perm[blockIdx.x * TILE + tid];
    __syncthreads();
    if (nodes[0] < 0) return;
    int t = ntype[nodes[0]];
#pragma unroll
    for (int c = 0; c < 4; ++c) {
        int v = tid + c * 256;
        int ns = v >> 5, ii = (v & 31) * 4;
        int node = nodes[ns];
        uint2 pk = make_uint2(0u, 0u);
        if (node >= 0) pk = *(const uint2*)(aggb + (size_t)node * HID + ii);
        *(uint2*)&xs[ns][ii] = pk;
    }
    __syncthreads();
    int wv = tid >> 6, lane = tid & 63;
    int lrow = lane & 15, lk = lane >> 4;
    bf16x8 af[2][4];
#pragma unroll
    for (int rt = 0; rt < 2; ++rt)
#pragma unroll
        for (int kk = 0; kk < 4; ++kk)
            af[rt][kk] = *(const bf16x8*)&xs[rt * 16 + lrow][kk * 32 + lk * 8];
    const unsigned short* wb0 = Wt + (size_t)t * HID * HID + (size_t)lrow * HID + lk * 8;
    float al = 1.f / (1.f + __expf(-skip[t]));
    float om = 1.f - al;
    float ov[2][2][4];   // [pp][half][q]
#pragma unroll
    for (int pp = 0; pp < 2; ++pp) {
        int ct = wv * 2 + pp;
        const unsigned short* wb = wb0 + (size_t)ct * 16 * HID;
        f32x4 a0 = {0.f, 0.f, 0.f, 0.f}, a1 = {0.f, 0.f, 0.f, 0.f};
#pragma unroll
        for (int kk = 0; kk < 4; ++kk) {
            bf16x8 bfr = *(const bf16x8*)(wb + kk * 32);
            a0 = __builtin_amdgcn_mfma_f32_16x16x32_bf16(af[0][kk], bfr, a0, 0, 0, 0);
            a1 = __builtin_amdgcn_mfma_f32_16x16x32_bf16(af[1][kk], bfr, a1, 0, 0, 0);
        }
        int col = ct * 16 + lrow;
#pragma unroll
        for (int q = 0; q < 4; ++q) {
            int n0 = nodes[lk * 4 + q], n1 = nodes[16 + lk * 4 + q];
            float s0 = a0[q] / (1.f + __expf(-a0[q]));
            float s1 = a1[q] / (1.f + __expf(-a1[q]));
            float x0 = (n0 >= 0) ? xin[(size_t)n0 * HID + col] : 0.f;
            float x1 = (n1 >= 0) ? xin[(size_t)n1 * HID + col] : 0.f;
            ov[pp][0][q] = s0 * al + x0 * om;
            ov[pp][1][q] = s1 * al + x1 * om;
        }
    }
#pragma unroll
    for (int half = 0; half < 2; ++half)
#pragma unroll
        for (int q = 0; q < 4; ++q) {
            float s = ov[0][half][q] + ov[1][half][q];
            float s2 = ov[0][half][q] * ov[0][half][q] + ov[1][half][q] * ov[1][half][q];
            s += __shfl_xor(s, 1); s += __shfl_xor(s, 2);
            s += __shfl_xor(s, 4); s += __shfl_xor(s, 8);
            s2 += __shfl_xor(s2, 1); s2 += __shfl_xor(s2, 2);
            s2 += __shfl_xor(s2, 4); s2 += __shfl_xor(s2, 8);
            if (lrow == 0) {
                int nd = half * 16 + lk * 4 + q;
                psum[nd][wv] = s;
                psq[nd][wv] = s2;
            }
        }
    __syncthreads();
    if (tid < TILE) {
        float s = psum[tid][0] + psum[tid][1] + psum[tid][2] + psum[tid][3];
        float s2 = psq[tid][0] + psq[tid][1] + psq[tid][2] + psq[tid][3];
        float mu = s * (1.f / HID);
        float var = s2 * (1.f / HID) - mu * mu;
        mu_s[tid] = mu;
        rv_s[tid] = rsqrtf(fmaxf(var, 0.f) + 1e-5f);
    }
    __syncthreads();
#pragma unroll
    for (int pp = 0; pp < 2; ++pp) {
        int col = (wv * 2 + pp) * 16 + lrow;
        float gg = g[col], bb = b[col];
#pragma unroll
        for (int q = 0; q < 4; ++q) {
            int i0 = lk * 4 + q, i1 = 16 + lk * 4 + q;
            int n0 = nodes[i0], n1 = nodes[i1];
            if (n0 >= 0) xout[(size_t)n0 * HID + col] = (ov[pp][0][q] - mu_s[i0]) * rv_s[i0] * gg + bb;
            if (n1 >= 0) xout[(size_t)n1 * HID + col] = (ov[pp][1][q] - mu_s[i1]) * rv_s[i1] * gg + bb;
        }
    }
}

// ---------- fused attention: per dst-window transform (MFMA) + softmax, LDS intermediate ----------
// Phase 1: per-tile loop, K/V/q prefetched for all 4 heads before the MFMA chain.
__global__ __launch_bounds__(512) void fused_attn_kernel(
    const unsigned short* __restrict__ Kb, const unsigned short* __restrict__ Vb,
    const unsigned short* __restrict__ Qb,
    const int* __restrict__ row_ptr, const int* __restrict__ deg,
    const int* __restrict__ btile_sd, const int* __restrict__ btile_lp,
    const int* __restrict__ btile_r, const int* __restrict__ ntb,
    const unsigned short* __restrict__ WattT, const unsigned short* __restrict__ WmsgT,
    unsigned short* __restrict__ aggb) {
    __shared__ unsigned short smg[CAP + 1][MPITCH];
    __shared__ float ssc[CAP + 1][SPITCH];
    int b = blockIdx.x;
    int wv = threadIdx.x >> 6, lane = threadIdx.x & 63;
    int ecol = lane & 15, lk = lane >> 4;
    int nt = ntb[b];
    int p0 = row_ptr[b * 16];
    const bf16x8 zz = {0, 0, 0, 0, 0, 0, 0, 0};

#pragma unroll
    for (int pass = 0; pass < 2; ++pass) {
        int hbase = pass * 4;
        // ---- phase 1: relation tiles -> LDS scores/mg ----
        for (int t = wv; t < nt; t += 8) {
            int ti = b * TPBMAX + t;
            int r = btile_r[ti];
            int sd = btile_sd[ti * 16 + ecol];
            int lp = btile_lp[ti * 16 + ecol];
            int s = sd & 0xFFFF, dd = ((unsigned)sd >> 16);
            // prefetch all 4 heads' K/V fragments + q words (independent loads in flight)
            bf16x8 bkh[4], bvh[4];
            uint2 qh[4];
#pragma unroll
            for (int hh = 0; hh < 4; ++hh) {
                int h = hbase + hh;
                bkh[hh] = zz; bvh[hh] = zz;
                if (lk < 2) {
                    bkh[hh] = *(const bf16x8*)(Kb + (size_t)s * HID + h * HS + lk * 8);
                    bvh[hh] = *(const bf16x8*)(Vb + (size_t)s * HID + h * HS + lk * 8);
                }
                qh[hh] = *(const uint2*)(Qb + (size_t)dd * HID + h * HS + lk * 4);
            }
#pragma unroll
            for (int hh = 0; hh < 4; ++hh) {
                int h = hbase + hh;
                bf16x8 aa = zz, am = zz;
                if (lk < 2) {
                    int wo = ((h * NR + r) * 16 + ecol) * 16 + lk * 8;
                    aa = *(const bf16x8*)(WattT + wo);
                    am = *(const bf16x8*)(WmsgT + wo);
                }
                f32x4 ck = {0.f, 0.f, 0.f, 0.f}, cm = {0.f, 0.f, 0.f, 0.f};
                ck = __builtin_amdgcn_mfma_f32_16x16x32_bf16(aa, bkh[hh], ck, 0, 0, 0);
                cm = __builtin_amdgcn_mfma_f32_16x16x32_bf16(am, bvh[hh], cm, 0, 0, 0);
                float q0 = __uint_as_float(qh[hh].x << 16);
                float q1 = __uint_as_float(qh[hh].x & 0xffff0000u);
                float q2 = __uint_as_float(qh[hh].y << 16);
                float q3 = __uint_as_float(qh[hh].y & 0xffff0000u);
                float xsc = ck[0] * q0 + ck[1] * q1 + ck[2] * q2 + ck[3] * q3;
                xsc += __shfl_xor(xsc, 16);
                xsc += __shfl_xor(xsc, 32);
                if (lk == 0) ssc[lp][hh] = xsc;
                uint2 pk2;
                pk2.x = (unsigned)f2bf(cm[0]) | ((unsigned)f2bf(cm[1]) << 16);
                pk2.y = (unsigned)f2bf(cm[2]) | ((unsigned)f2bf(cm[3]) << 16);
                *(uint2*)&smg[lp][hh * 16 + lk * 4] = pk2;
            }
        }
        __syncthreads();
        // ---- phase 2: per-dst online softmax over LDS ----
        int h2 = lane >> 4, o = lane & 15;
#pragma unroll
        for (int i = 0; i < 2; ++i) {
            int d = b * 16 + wv * 2 + i;
            int lo = row_ptr[d] - p0;
            int dg = deg[d];
            float m = -INFINITY, den = 0.f, acc = 0.f;
            for (int e = 0; e < dg; ++e) {
                int lp = lo + e;
                float a = ssc[lp][h2];
                float gv = bf2f(smg[lp][h2 * 16 + o]);
                float mn = fmaxf(m, a);
                float scale = __expf(m - mn);
                float ex = __expf(a - mn);
                den = den * scale + ex;
                acc = acc * scale + ex * gv;
                m = mn;
            }
            aggb[(size_t)d * HID + (hbase + h2) * HS + o] = f2bf(acc / (den + 1e-16f));
        }
        __syncthreads();
    }
}

extern "C" void kernel_launch(void* const* d_in, const int* in_sizes, int n_in,
                              void* d_out, int out_size, void* d_ws, size_t ws_size,
                              hipStream_t stream) {
    const float* x     = (const float*)d_in[0];
    const int*   eidx  = (const int*)d_in[1];
    const int*   ntype = (const int*)d_in[2];
    const int*   etype = (const int*)d_in[3];
    const float* Wk    = (const float*)d_in[4];
    const float* Wq    = (const float*)d_in[5];
    const float* Wv    = (const float*)d_in[6];
    const float* Wa    = (const float*)d_in[7];
    const float* pri   = (const float*)d_in[8];
    const float* Watt  = (const float*)d_in[9];
    const float* Wmsg  = (const float*)d_in[10];
    const float* skip  = (const float*)d_in[11];
    const float* ln_g  = (const float*)d_in[12];
    const float* ln_b  = (const float*)d_in[13];
    const float* Wff   = (const float*)d_in[14];
    const float* bff   = (const float*)d_in[15];
    const int* src = eidx;
    const int* dst = eidx + N_EDGES;

    char* ws = (char*)d_ws;
    size_t szN = (size_t)N_NODES * HID * sizeof(float);        // 25.6 MB
    float* embA = (float*)(ws);                                // layer-0 out
    unsigned short* AGGb = (unsigned short*)(ws + szN);        // bf16 agg (12.8 MB)
    char*  kvq  = ws + 2 * szN;
    unsigned short* Kbf = (unsigned short*)kvq;                // 12.8 MB each
    unsigned short* Vbf = (unsigned short*)(kvq + (size_t)N_NODES * HID * 2);
    unsigned short* Qbf = (unsigned short*)(kvq + 2 * (size_t)N_NODES * HID * 2);
    float* l1out = (float*)kvq;                                // aliases K+V (dead by then)
    char*  p    = kvq + 3 * (size_t)N_NODES * HID * 2;
    int* perm    = (int*)p;  p += (size_t)PERM_SZ * 4;
    int* cnt     = (int*)p;  p += TN * 4;
    int* cursor  = (int*)p;  p += TN * 4;
    int* row_ptr = (int*)p;  p += (size_t)N_NODES * 4;
    int* cnt_dst = (int*)p;  p += (size_t)N_NODES * 4;
    int* cur_dst = (int*)p;  p += (size_t)N_NODES * 4;
    int* bsum    = (int*)p;  p += 256 * 4;
    int* csr_sd  = (int*)p;  p += (size_t)N_EDGES * 4;
    int* csr_et  = (int*)p;  p += (size_t)N_EDGES * 4;
    int* btile_sd = (int*)p; p += (size_t)NB * TPBMAX * 16 * 4;   // 5.2 MB
    int* btile_lp = (int*)p; p += (size_t)NB * TPBMAX * 16 * 4;   // 5.2 MB
    int* btile_r  = (int*)p; p += (size_t)NB * TPBMAX * 4;
    int* ntb      = (int*)p; p += (size_t)NB * 4;
    size_t wmat = (size_t)HID * HID;
    unsigned short* WkT  = (unsigned short*)p;  p += 2 * TN * wmat * 2;
    unsigned short* WqT  = (unsigned short*)p;  p += 2 * TN * wmat * 2;
    unsigned short* WvT  = (unsigned short*)p;  p += 2 * TN * wmat * 2;
    unsigned short* WaT  = (unsigned short*)p;  p += 2 * TN * wmat * 2;
    unsigned short* WffT = (unsigned short*)p;  p += wmat * 2;
    unsigned short* WattT = (unsigned short*)p; p += 2 * 64 * 256 * 2;
    unsigned short* WmsgT = (unsigned short*)p; p += 2 * 64 * 256 * 2;

    // weight conversion (once per launch): 65 matrices in one kernel
    wconv_all_kernel<<<65 * 8, 256, 0, stream>>>(Wk, Wq, Wv, Wa, Wff,
                                                 WkT, WqT, WvT, WaT, WffT);
    wsmall_conv<<<128, 256, 0, stream>>>(Watt, pri, WattT);     // pri/4 baked in
    wsmall_conv<<<128, 256, 0, stream>>>(Wmsg, nullptr, WmsgT);

    // node type sort (once)
    hipMemsetAsync(cnt, 0, TN * 4, stream);
    hipMemsetAsync(perm, 0xFF, (size_t)PERM_SZ * 4, stream);
    hist_kernel<<<(N_NODES + 255) / 256, 256, 0, stream>>>(ntype, cnt);
    scan_kernel<<<1, 64, 0, stream>>>(cnt, cursor);
    scatter_kernel<<<(N_NODES + 255) / 256, 256, 0, stream>>>(ntype, cursor, perm);

    // edge CSR by dst, then per-window relation tiles (once)
    hipMemsetAsync(cnt_dst, 0, (size_t)N_NODES * 4, stream);
    hist_dst_kernel<<<(N_EDGES + 255) / 256, 256, 0, stream>>>(dst, cnt_dst);
    scan_block_kernel<<<SCAN_BLKS, 256, 0, stream>>>(cnt_dst, row_ptr, bsum);
    scan_top_kernel<<<1, 256, 0, stream>>>(bsum);
    scan_add_kernel<<<SCAN_BLKS, 256, 0, stream>>>(row_ptr, bsum, cur_dst);
    csr_scatter_kernel<<<(N_EDGES + 255) / 256, 256, 0, stream>>>(src, dst, etype, cur_dst,
                                                                  csr_sd, csr_et);
    btile_build<<<NB, 64, 0, stream>>>(row_ptr, csr_sd, csr_et,
                                       btile_sd, btile_lp, btile_r, ntb);

    for (int l = 0; l < 2; ++l) {
        const float* xin = l ? embA : x;
        float* xout = l ? l1out : embA;
        const float* skip_l = skip + (size_t)l * TN;
        const float* g_l    = ln_g + (size_t)l * HID;
        const float* b_l    = ln_b + (size_t)l * HID;
        const unsigned short* WkT_l = WkT + (size_t)l * TN * wmat;
        const unsigned short* WqT_l = WqT + (size_t)l * TN * wmat;
        const unsigned short* WvT_l = WvT + (size_t)l * TN * wmat;
        const unsigned short* WaT_l = WaT + (size_t)l * TN * wmat;
        const unsigned short* WattT_l = WattT + (size_t)l * 64 * 256;
        const unsigned short* WmsgT_l = WmsgT + (size_t)l * 64 * 256;

        gemm3_mfma<<<MAXTILES, 256, 0, stream>>>(xin, perm, ntype, WkT_l, WqT_l, WvT_l,
                                                 Kbf, Qbf, Vbf);
        fused_attn_kernel<<<NB, 512, 0, stream>>>(Kbf, Vbf, Qbf, row_ptr, cnt_dst,
                                                  btile_sd, btile_lp, btile_r, ntb,
                                                  WattT_l, WmsgT_l, AGGb);
        // Wa typed GEMM + SiLU + gated residual + LayerNorm (fused, bf16 agg in)
        gemm1_ln_mfma<<<MAXTILES, 256, 0, stream>>>(AGGb, perm, ntype, WaT_l, xin,
                                                    skip_l, g_l, b_l, xout);
    }
    // final FF: l1out @ Wff + bff -> d_out
    gemm1_mfma<<<(N_NODES + TILE - 1) / TILE, 256, 0, stream>>>(l1out, nullptr, ntype, WffT,
                                                                bff, (float*)d_out);
}

// Round 19
// 419.535 us; speedup vs baseline: 1.0757x; 1.0757x over previous
//
#include <hip/hip_runtime.h>
#include <hip/hip_bf16.h>
#include <math.h>

#define N_NODES 50000
#define N_EDGES 400000
#define HID 128
#define NH 8
#define HS 16
#define TN 8
#define NR 8
#define TILE 32
#define MAXTILES 1571
#define PERM_SZ (MAXTILES * TILE)
#define SCAN_BLKS ((N_NODES + 255) / 256)   // 196
#define NB 3125                              // dst windows of 16 nodes (exact)
#define TPBMAX 26                            // max 16-edge tiles per window
#define CAP 240                              // max edges per window (~10 sigma)
#define MPITCH 68                            // smg row pitch in shorts
#define SPITCH 5                             // ssc row pitch in floats

typedef __attribute__((ext_vector_type(8))) short bf16x8;
typedef __attribute__((ext_vector_type(4))) float f32x4;

__device__ __forceinline__ unsigned short f2bf(float f) {
    __hip_bfloat16 h = __float2bfloat16(f);
    return *reinterpret_cast<unsigned short*>(&h);
}
__device__ __forceinline__ float bf2f(unsigned short u) {
    return __uint_as_float((unsigned)u << 16);
}

// ---------- node type sort (LDS-aggregated counting sort) ----------
__global__ void hist_kernel(const int* __restrict__ ntype, int* __restrict__ cnt) {
    __shared__ int l[TN];
    if (threadIdx.x < TN) l[threadIdx.x] = 0;
    __syncthreads();
    int i = blockIdx.x * 256 + threadIdx.x;
    if (i < N_NODES) atomicAdd(&l[ntype[i]], 1);
    __syncthreads();
    if (threadIdx.x < TN) atomicAdd(&cnt[threadIdx.x], l[threadIdx.x]);
}
__global__ void scan_kernel(const int* __restrict__ cnt, int* __restrict__ cursor) {
    if (threadIdx.x == 0 && blockIdx.x == 0) {
        int acc = 0;
        for (int t = 0; t < TN; ++t) {
            cursor[t] = acc;
            acc += ((cnt[t] + TILE - 1) / TILE) * TILE;
        }
    }
}
__global__ void scatter_kernel(const int* __restrict__ ntype, int* __restrict__ cursor,
                               int* __restrict__ perm) {
    __shared__ int lcnt[TN], lbase[TN];
    if (threadIdx.x < TN) lcnt[threadIdx.x] = 0;
    __syncthreads();
    int i = blockIdx.x * 256 + threadIdx.x;
    int t = 0, off = 0;
    if (i < N_NODES) {
        t = ntype[i];
        off = atomicAdd(&lcnt[t], 1);
    }
    __syncthreads();
    if (threadIdx.x < TN)
        lbase[threadIdx.x] = atomicAdd(&cursor[threadIdx.x], lcnt[threadIdx.x]);
    __syncthreads();
    if (i < N_NODES) perm[lbase[t] + off] = i;
}

// ---------- edge CSR build (sort by dst) ----------
__global__ void hist_dst_kernel(const int* __restrict__ dst, int* __restrict__ cnt) {
    int e = blockIdx.x * 256 + threadIdx.x;
    if (e < N_EDGES) atomicAdd(&cnt[dst[e]], 1);
}
__global__ void scan_block_kernel(const int* __restrict__ cnt, int* __restrict__ excl,
                                  int* __restrict__ bsum) {
    __shared__ int s[256];
    int tid = threadIdx.x;
    int i = blockIdx.x * 256 + tid;
    int v = (i < N_NODES) ? cnt[i] : 0;
    s[tid] = v;
    __syncthreads();
    for (int off = 1; off < 256; off <<= 1) {
        int t = (tid >= off) ? s[tid - off] : 0;
        __syncthreads();
        s[tid] += t;
        __syncthreads();
    }
    if (i < N_NODES) excl[i] = s[tid] - v;
    if (tid == 255) bsum[blockIdx.x] = s[255];
}
__global__ void scan_top_kernel(int* __restrict__ bsum) {
    __shared__ int s[256];
    int tid = threadIdx.x;
    int v = (tid < SCAN_BLKS) ? bsum[tid] : 0;
    s[tid] = v;
    __syncthreads();
    for (int off = 1; off < 256; off <<= 1) {
        int t = (tid >= off) ? s[tid - off] : 0;
        __syncthreads();
        s[tid] += t;
        __syncthreads();
    }
    if (tid < SCAN_BLKS) bsum[tid] = s[tid] - v;   // exclusive
}
__global__ void scan_add_kernel(int* __restrict__ excl, const int* __restrict__ bsum,
                                int* __restrict__ cursor) {
    int i = blockIdx.x * 256 + threadIdx.x;
    if (i < N_NODES) {
        int v = excl[i] + bsum[blockIdx.x];
        excl[i] = v;        // becomes row_ptr
        cursor[i] = v;
    }
}
// place edges at CSR positions (by dst)
__global__ void csr_scatter_kernel(const int* __restrict__ src, const int* __restrict__ dst,
                                   const int* __restrict__ etype, int* __restrict__ cur_dst,
                                   int* __restrict__ csr_sd, int* __restrict__ csr_et) {
    int e = blockIdx.x * 256 + threadIdx.x;
    if (e < N_EDGES) {
        int p = atomicAdd(&cur_dst[dst[e]], 1);
        csr_sd[p] = src[e] | (dst[e] << 16);
        csr_et[p] = etype[e];
    }
}

// ---------- per-window relation tile build (once) ----------
__global__ void btile_build(const int* __restrict__ row_ptr,
                            const int* __restrict__ csr_sd, const int* __restrict__ csr_et,
                            int* __restrict__ btile_sd, int* __restrict__ btile_lp,
                            int* __restrict__ btile_r, int* __restrict__ ntb) {
    int b = blockIdx.x;
    int lane = threadIdx.x;              // 64 threads = 1 wave
    int p0 = row_ptr[b * 16];
    int p1 = (b == NB - 1) ? N_EDGES : row_ptr[b * 16 + 16];
    int cnt = 0;
    if (lane < 8) {
        for (int p = p0; p < p1; ++p) cnt += (csr_et[p] == lane);
    }
    int tiles = (cnt + 15) >> 4;
    int pre = 0, total = 0;
    for (int k = 0; k < 8; ++k) {
        int tk = __shfl(tiles, k);
        if (k < lane) pre += tk;
        total += tk;
    }
    if (lane == 0) ntb[b] = total;
    if (lane < 8) {
        int tbase = b * TPBMAX + pre;
        for (int t = 0; t < tiles; ++t) btile_r[tbase + t] = lane;
        int off = 0;
        for (int p = p0; p < p1; ++p) {
            if (csr_et[p] == lane) {
                int idx = (tbase + (off >> 4)) * 16 + (off & 15);
                btile_sd[idx] = csr_sd[p];
                btile_lp[idx] = p - p0;
                ++off;
            }
        }
        for (; off < tiles * 16; ++off) {
            int idx = (tbase + (off >> 4)) * 16 + (off & 15);
            btile_sd[idx] = 0;
            btile_lp[idx] = CAP;         // scratch slot
        }
    }
}

// ---------- weight converts ----------
__global__ void wconv_all_kernel(const float* __restrict__ Wk, const float* __restrict__ Wq,
                                 const float* __restrict__ Wv, const float* __restrict__ Wa,
                                 const float* __restrict__ Wff,
                                 unsigned short* __restrict__ WkT, unsigned short* __restrict__ WqT,
                                 unsigned short* __restrict__ WvT, unsigned short* __restrict__ WaT,
                                 unsigned short* __restrict__ WffT) {
    int blk = blockIdx.x;                 // [0, 65*8)
    int m16 = blk >> 3;                   // 0..64 ; 64 => Wff
    int seg = blk & 7;
    const float* w;
    unsigned short* o;
    if (m16 < 64) {
        int grp = m16 >> 4, mat = m16 & 15;
        const float* Wsrc = grp == 0 ? Wk : (grp == 1 ? Wq : (grp == 2 ? Wv : Wa));
        unsigned short* Wdst = grp == 0 ? WkT : (grp == 1 ? WqT : (grp == 2 ? WvT : WaT));
        w = Wsrc + (size_t)mat * HID * HID;
        o = Wdst + (size_t)mat * HID * HID;
    } else {
        w = Wff;
        o = WffT;
    }
#pragma unroll
    for (int c = 0; c < 8; ++c) {
        int idx = seg * 2048 + c * 256 + threadIdx.x;
        int i = idx >> 7, j = idx & 127;
        o[j * HID + i] = f2bf(w[idx]);
    }
}
__global__ void wsmall_conv(const float* __restrict__ W, const float* __restrict__ pri,
                            unsigned short* __restrict__ out) {
    int blk = blockIdx.x;                 // l*64 + h*8 + r
    int tid = threadIdx.x;                // 256 = 16x16
    int i = tid >> 4, o = tid & 15;
    float s = pri ? pri[blk] * 0.25f : 1.f;
    out[blk * 256 + o * 16 + i] = f2bf(W[blk * 256 + i * 16 + o] * s);
}

// ---------- MFMA typed GEMM: 32 nodes x 128 outs; K,Q,V all bf16 ----------
__global__ __launch_bounds__(256) void gemm3_mfma(
    const float* __restrict__ x, const int* __restrict__ perm, const int* __restrict__ ntype,
    const unsigned short* __restrict__ WkT, const unsigned short* __restrict__ WqT,
    const unsigned short* __restrict__ WvT,
    unsigned short* __restrict__ Kb, unsigned short* __restrict__ Qb,
    unsigned short* __restrict__ Vb) {
    __shared__ unsigned short xs[TILE][HID + 8];
    __shared__ int nodes[TILE];
    int tid = threadIdx.x;
    if (tid < TILE) nodes[tid] = perm[blockIdx.x * TILE + tid];
    __syncthreads();
    if (nodes[0] < 0) return;
    int t = ntype[nodes[0]];
#pragma unroll
    for (int c = 0; c < 4; ++c) {
        int v = tid + c * 256;
        int ns = v >> 5, ii = (v & 31) * 4;
        int node = nodes[ns];
        float4 val = (node >= 0) ? *(const float4*)(x + (size_t)node * HID + ii)
                                 : make_float4(0.f, 0.f, 0.f, 0.f);
        uint2 pk;
        pk.x = (unsigned)f2bf(val.x) | ((unsigned)f2bf(val.y) << 16);
        pk.y = (unsigned)f2bf(val.z) | ((unsigned)f2bf(val.w) << 16);
        *(uint2*)&xs[ns][ii] = pk;
    }
    __syncthreads();
    int wv = tid >> 6, lane = tid & 63;
    int lrow = lane & 15, lk = lane >> 4;
    bf16x8 af[2][4];
#pragma unroll
    for (int rt = 0; rt < 2; ++rt)
#pragma unroll
        for (int kk = 0; kk < 4; ++kk)
            af[rt][kk] = *(const bf16x8*)&xs[rt * 16 + lrow][kk * 32 + lk * 8];
    size_t woff = (size_t)t * HID * HID + (size_t)lrow * HID + lk * 8;
#pragma unroll
    for (int pp = 0; pp < 6; ++pp) {
        int p = wv * 6 + pp;
        int mat = p >> 3, ct = p & 7;
        const unsigned short* wb =
            (mat == 0 ? WkT : (mat == 1 ? WqT : WvT)) + woff + (size_t)ct * 16 * HID;
        unsigned short* ob = (mat == 0) ? Kb : (mat == 1 ? Qb : Vb);
        f32x4 a0 = {0.f, 0.f, 0.f, 0.f}, a1 = {0.f, 0.f, 0.f, 0.f};
#pragma unroll
        for (int kk = 0; kk < 4; ++kk) {
            bf16x8 bfr = *(const bf16x8*)(wb + kk * 32);
            a0 = __builtin_amdgcn_mfma_f32_16x16x32_bf16(af[0][kk], bfr, a0, 0, 0, 0);
            a1 = __builtin_amdgcn_mfma_f32_16x16x32_bf16(af[1][kk], bfr, a1, 0, 0, 0);
        }
        int col = ct * 16 + lrow;
#pragma unroll
        for (int q = 0; q < 4; ++q) {
            int r0 = lk * 4 + q;
            int n0 = nodes[r0], n1 = nodes[16 + r0];
            if (n0 >= 0) ob[(size_t)n0 * HID + col] = f2bf(a0[q]);
            if (n1 >= 0) ob[(size_t)n1 * HID + col] = f2bf(a1[q]);
        }
    }
}

// ---------- MFMA GEMM (plain, fp32 in, fp32 out, +bias) for final FF ----------
__global__ __launch_bounds__(256) void gemm1_mfma(
    const float* __restrict__ x, const int* __restrict__ perm, const int* __restrict__ ntype,
    const unsigned short* __restrict__ Wt, const float* __restrict__ bias,
    float* __restrict__ out) {
    __shared__ unsigned short xs[TILE][HID + 8];
    __shared__ int nodes[TILE];
    int tid = threadIdx.x;
    if (tid < TILE) {
        int n;
        if (perm) n = perm[blockIdx.x * TILE + tid];
        else { n = blockIdx.x * TILE + tid; if (n >= N_NODES) n = -1; }
        nodes[tid] = n;
    }
    __syncthreads();
    if (nodes[0] < 0) return;
    int t = perm ? ntype[nodes[0]] : 0;
#pragma unroll
    for (int c = 0; c < 4; ++c) {
        int v = tid + c * 256;
        int ns = v >> 5, ii = (v & 31) * 4;
        int node = nodes[ns];
        float4 val = (node >= 0) ? *(const float4*)(x + (size_t)node * HID + ii)
                                 : make_float4(0.f, 0.f, 0.f, 0.f);
        uint2 pk;
        pk.x = (unsigned)f2bf(val.x) | ((unsigned)f2bf(val.y) << 16);
        pk.y = (unsigned)f2bf(val.z) | ((unsigned)f2bf(val.w) << 16);
        *(uint2*)&xs[ns][ii] = pk;
    }
    __syncthreads();
    int wv = tid >> 6, lane = tid & 63;
    int lrow = lane & 15, lk = lane >> 4;
    bf16x8 af[2][4];
#pragma unroll
    for (int rt = 0; rt < 2; ++rt)
#pragma unroll
        for (int kk = 0; kk < 4; ++kk)
            af[rt][kk] = *(const bf16x8*)&xs[rt * 16 + lrow][kk * 32 + lk * 8];
    const unsigned short* wb0 = Wt + (size_t)t * HID * HID + (size_t)lrow * HID + lk * 8;
#pragma unroll
    for (int pp = 0; pp < 2; ++pp) {
        int ct = wv * 2 + pp;
        const unsigned short* wb = wb0 + (size_t)ct * 16 * HID;
        f32x4 a0 = {0.f, 0.f, 0.f, 0.f}, a1 = {0.f, 0.f, 0.f, 0.f};
#pragma unroll
        for (int kk = 0; kk < 4; ++kk) {
            bf16x8 bfr = *(const bf16x8*)(wb + kk * 32);
            a0 = __builtin_amdgcn_mfma_f32_16x16x32_bf16(af[0][kk], bfr, a0, 0, 0, 0);
            a1 = __builtin_amdgcn_mfma_f32_16x16x32_bf16(af[1][kk], bfr, a1, 0, 0, 0);
        }
        float bv = bias ? bias[ct * 16 + lrow] : 0.f;
#pragma unroll
        for (int q = 0; q < 4; ++q) {
            int r0 = lk * 4 + q;
            int n0 = nodes[r0], n1 = nodes[16 + r0];
            if (n0 >= 0) out[(size_t)n0 * HID + ct * 16 + lrow] = a0[q] + bv;
            if (n1 >= 0) out[(size_t)n1 * HID + ct * 16 + lrow] = a1[q] + bv;
        }
    }
}

// ---------- MFMA typed GEMM (bf16 agg in) + SiLU + gated residual + LayerNorm ----------
__global__ __launch_bounds__(256) void gemm1_ln_mfma(
    const unsigned short* __restrict__ aggb, const int* __restrict__ perm,
    const int* __restrict__ ntype, const unsigned short* __restrict__ Wt,
    const float* __restrict__ xin, const float* __restrict__ skip,
    const float* __restrict__ g, const float* __restrict__ b, float* __restrict__ xout) {
    __shared__ unsigned short xs[TILE][HID + 8];
    __shared__ int nodes[TILE];
    __shared__ float psum[TILE][4], psq[TILE][4];
    __shared__ float mu_s[TILE], rv_s[TILE];
    int tid = threadIdx.x;
    if (tid < TILE) nodes[tid] = perm[blockIdx.x * TILE + tid];
    __syncthreads();
    if (nodes[0] < 0) return;
    int t = ntype[nodes[0]];
#pragma unroll
    for (int c = 0; c < 4; ++c) {
        int v = tid + c * 256;
        int ns = v >> 5, ii = (v & 31) * 4;
        int node = nodes[ns];
        uint2 pk = make_uint2(0u, 0u);
        if (node >= 0) pk = *(const uint2*)(aggb + (size_t)node * HID + ii);
        *(uint2*)&xs[ns][ii] = pk;
    }
    __syncthreads();
    int wv = tid >> 6, lane = tid & 63;
    int lrow = lane & 15, lk = lane >> 4;
    bf16x8 af[2][4];
#pragma unroll
    for (int rt = 0; rt < 2; ++rt)
#pragma unroll
        for (int kk = 0; kk < 4; ++kk)
            af[rt][kk] = *(const bf16x8*)&xs[rt * 16 + lrow][kk * 32 + lk * 8];
    const unsigned short* wb0 = Wt + (size_t)t * HID * HID + (size_t)lrow * HID + lk * 8;
    float al = 1.f / (1.f + __expf(-skip[t]));
    float om = 1.f - al;
    float ov[2][2][4];   // [pp][half][q]
#pragma unroll
    for (int pp = 0; pp < 2; ++pp) {
        int ct = wv * 2 + pp;
        const unsigned short* wb = wb0 + (size_t)ct * 16 * HID;
        f32x4 a0 = {0.f, 0.f, 0.f, 0.f}, a1 = {0.f, 0.f, 0.f, 0.f};
#pragma unroll
        for (int kk = 0; kk < 4; ++kk) {
            bf16x8 bfr = *(const bf16x8*)(wb + kk * 32);
            a0 = __builtin_amdgcn_mfma_f32_16x16x32_bf16(af[0][kk], bfr, a0, 0, 0, 0);
            a1 = __builtin_amdgcn_mfma_f32_16x16x32_bf16(af[1][kk], bfr, a1, 0, 0, 0);
        }
        int col = ct * 16 + lrow;
#pragma unroll
        for (int q = 0; q < 4; ++q) {
            int n0 = nodes[lk * 4 + q], n1 = nodes[16 + lk * 4 + q];
            float s0 = a0[q] / (1.f + __expf(-a0[q]));
            float s1 = a1[q] / (1.f + __expf(-a1[q]));
            float x0 = (n0 >= 0) ? xin[(size_t)n0 * HID + col] : 0.f;
            float x1 = (n1 >= 0) ? xin[(size_t)n1 * HID + col] : 0.f;
            ov[pp][0][q] = s0 * al + x0 * om;
            ov[pp][1][q] = s1 * al + x1 * om;
        }
    }
#pragma unroll
    for (int half = 0; half < 2; ++half)
#pragma unroll
        for (int q = 0; q < 4; ++q) {
            float s = ov[0][half][q] + ov[1][half][q];
            float s2 = ov[0][half][q] * ov[0][half][q] + ov[1][half][q] * ov[1][half][q];
            s += __shfl_xor(s, 1); s += __shfl_xor(s, 2);
            s += __shfl_xor(s, 4); s += __shfl_xor(s, 8);
            s2 += __shfl_xor(s2, 1); s2 += __shfl_xor(s2, 2);
            s2 += __shfl_xor(s2, 4); s2 += __shfl_xor(s2, 8);
            if (lrow == 0) {
                int nd = half * 16 + lk * 4 + q;
                psum[nd][wv] = s;
                psq[nd][wv] = s2;
            }
        }
    __syncthreads();
    if (tid < TILE) {
        float s = psum[tid][0] + psum[tid][1] + psum[tid][2] + psum[tid][3];
        float s2 = psq[tid][0] + psq[tid][1] + psq[tid][2] + psq[tid][3];
        float mu = s * (1.f / HID);
        float var = s2 * (1.f / HID) - mu * mu;
        mu_s[tid] = mu;
        rv_s[tid] = rsqrtf(fmaxf(var, 0.f) + 1e-5f);
    }
    __syncthreads();
#pragma unroll
    for (int pp = 0; pp < 2; ++pp) {
        int col = (wv * 2 + pp) * 16 + lrow;
        float gg = g[col], bb = b[col];
#pragma unroll
        for (int q = 0; q < 4; ++q) {
            int i0 = lk * 4 + q, i1 = 16 + lk * 4 + q;
            int n0 = nodes[i0], n1 = nodes[i1];
            if (n0 >= 0) xout[(size_t)n0 * HID + col] = (ov[pp][0][q] - mu_s[i0]) * rv_s[i0] * gg + bb;
            if (n1 >= 0) xout[(size_t)n1 * HID + col] = (ov[pp][1][q] - mu_s[i1]) * rv_s[i1] * gg + bb;
        }
    }
}

// ---------- fused attention: per dst-window transform (MFMA) + softmax, LDS intermediate ----------
// Phase 1: per-tile loop (metadata hoisted) + unrolled 4-head inner loop (r16 structure).
__global__ __launch_bounds__(512) void fused_attn_kernel(
    const unsigned short* __restrict__ Kb, const unsigned short* __restrict__ Vb,
    const unsigned short* __restrict__ Qb,
    const int* __restrict__ row_ptr, const int* __restrict__ deg,
    const int* __restrict__ btile_sd, const int* __restrict__ btile_lp,
    const int* __restrict__ btile_r, const int* __restrict__ ntb,
    const unsigned short* __restrict__ WattT, const unsigned short* __restrict__ WmsgT,
    unsigned short* __restrict__ aggb) {
    __shared__ unsigned short smg[CAP + 1][MPITCH];
    __shared__ float ssc[CAP + 1][SPITCH];
    int b = blockIdx.x;
    int wv = threadIdx.x >> 6, lane = threadIdx.x & 63;
    int ecol = lane & 15, lk = lane >> 4;
    int nt = ntb[b];
    int p0 = row_ptr[b * 16];
    const bf16x8 zz = {0, 0, 0, 0, 0, 0, 0, 0};

#pragma unroll
    for (int pass = 0; pass < 2; ++pass) {
        int hbase = pass * 4;
        // ---- phase 1: relation tiles -> LDS scores/mg ----
        for (int t = wv; t < nt; t += 8) {
            int ti = b * TPBMAX + t;
            int r = btile_r[ti];
            int sd = btile_sd[ti * 16 + ecol];
            int lp = btile_lp[ti * 16 + ecol];
            int s = sd & 0xFFFF, dd = ((unsigned)sd >> 16);
#pragma unroll
            for (int hh = 0; hh < 4; ++hh) {
                int h = hbase + hh;
                bf16x8 bk = zz, bv = zz, aa = zz, am = zz;
                if (lk < 2) {
                    bk = *(const bf16x8*)(Kb + (size_t)s * HID + h * HS + lk * 8);
                    bv = *(const bf16x8*)(Vb + (size_t)s * HID + h * HS + lk * 8);
                    int wo = ((h * NR + r) * 16 + ecol) * 16 + lk * 8;
                    aa = *(const bf16x8*)(WattT + wo);
                    am = *(const bf16x8*)(WmsgT + wo);
                }
                f32x4 ck = {0.f, 0.f, 0.f, 0.f}, cm = {0.f, 0.f, 0.f, 0.f};
                ck = __builtin_amdgcn_mfma_f32_16x16x32_bf16(aa, bk, ck, 0, 0, 0);
                cm = __builtin_amdgcn_mfma_f32_16x16x32_bf16(am, bv, cm, 0, 0, 0);
                uint2 qraw = *(const uint2*)(Qb + (size_t)dd * HID + h * HS + lk * 4);
                float q0 = __uint_as_float(qraw.x << 16);
                float q1 = __uint_as_float(qraw.x & 0xffff0000u);
                float q2 = __uint_as_float(qraw.y << 16);
                float q3 = __uint_as_float(qraw.y & 0xffff0000u);
                float xsc = ck[0] * q0 + ck[1] * q1 + ck[2] * q2 + ck[3] * q3;
                xsc += __shfl_xor(xsc, 16);
                xsc += __shfl_xor(xsc, 32);
                if (lk == 0) ssc[lp][hh] = xsc;
                uint2 pk2;
                pk2.x = (unsigned)f2bf(cm[0]) | ((unsigned)f2bf(cm[1]) << 16);
                pk2.y = (unsigned)f2bf(cm[2]) | ((unsigned)f2bf(cm[3]) << 16);
                *(uint2*)&smg[lp][hh * 16 + lk * 4] = pk2;
            }
        }
        __syncthreads();
        // ---- phase 2: per-dst online softmax over LDS ----
        int h2 = lane >> 4, o = lane & 15;
#pragma unroll
        for (int i = 0; i < 2; ++i) {
            int d = b * 16 + wv * 2 + i;
            int lo = row_ptr[d] - p0;
            int dg = deg[d];
            float m = -INFINITY, den = 0.f, acc = 0.f;
            for (int e = 0; e < dg; ++e) {
                int lp = lo + e;
                float a = ssc[lp][h2];
                float gv = bf2f(smg[lp][h2 * 16 + o]);
                float mn = fmaxf(m, a);
                float scale = __expf(m - mn);
                float ex = __expf(a - mn);
                den = den * scale + ex;
                acc = acc * scale + ex * gv;
                m = mn;
            }
            aggb[(size_t)d * HID + (hbase + h2) * HS + o] = f2bf(acc / (den + 1e-16f));
        }
        __syncthreads();
    }
}

extern "C" void kernel_launch(void* const* d_in, const int* in_sizes, int n_in,
                              void* d_out, int out_size, void* d_ws, size_t ws_size,
                              hipStream_t stream) {
    const float* x     = (const float*)d_in[0];
    const int*   eidx  = (const int*)d_in[1];
    const int*   ntype = (const int*)d_in[2];
    const int*   etype = (const int*)d_in[3];
    const float* Wk    = (const float*)d_in[4];
    const float* Wq    = (const float*)d_in[5];
    const float* Wv    = (const float*)d_in[6];
    const float* Wa    = (const float*)d_in[7];
    const float* pri   = (const float*)d_in[8];
    const float* Watt  = (const float*)d_in[9];
    const float* Wmsg  = (const float*)d_in[10];
    const float* skip  = (const float*)d_in[11];
    const float* ln_g  = (const float*)d_in[12];
    const float* ln_b  = (const float*)d_in[13];
    const float* Wff   = (const float*)d_in[14];
    const float* bff   = (const float*)d_in[15];
    const int* src = eidx;
    const int* dst = eidx + N_EDGES;

    char* ws = (char*)d_ws;
    size_t szN = (size_t)N_NODES * HID * sizeof(float);        // 25.6 MB
    float* embA = (float*)(ws);                                // layer-0 out
    unsigned short* AGGb = (unsigned short*)(ws + szN);        // bf16 agg (12.8 MB)
    char*  kvq  = ws + 2 * szN;
    unsigned short* Kbf = (unsigned short*)kvq;                // 12.8 MB each
    unsigned short* Vbf = (unsigned short*)(kvq + (size_t)N_NODES * HID * 2);
    unsigned short* Qbf = (unsigned short*)(kvq + 2 * (size_t)N_NODES * HID * 2);
    float* l1out = (float*)kvq;                                // aliases K+V (dead by then)
    char*  p    = kvq + 3 * (size_t)N_NODES * HID * 2;
    int* perm    = (int*)p;  p += (size_t)PERM_SZ * 4;
    int* cnt     = (int*)p;  p += TN * 4;
    int* cursor  = (int*)p;  p += TN * 4;
    int* row_ptr = (int*)p;  p += (size_t)N_NODES * 4;
    int* cnt_dst = (int*)p;  p += (size_t)N_NODES * 4;
    int* cur_dst = (int*)p;  p += (size_t)N_NODES * 4;
    int* bsum    = (int*)p;  p += 256 * 4;
    int* csr_sd  = (int*)p;  p += (size_t)N_EDGES * 4;
    int* csr_et  = (int*)p;  p += (size_t)N_EDGES * 4;
    int* btile_sd = (int*)p; p += (size_t)NB * TPBMAX * 16 * 4;   // 5.2 MB
    int* btile_lp = (int*)p; p += (size_t)NB * TPBMAX * 16 * 4;   // 5.2 MB
    int* btile_r  = (int*)p; p += (size_t)NB * TPBMAX * 4;
    int* ntb      = (int*)p; p += (size_t)NB * 4;
    size_t wmat = (size_t)HID * HID;
    unsigned short* WkT  = (unsigned short*)p;  p += 2 * TN * wmat * 2;
    unsigned short* WqT  = (unsigned short*)p;  p += 2 * TN * wmat * 2;
    unsigned short* WvT  = (unsigned short*)p;  p += 2 * TN * wmat * 2;
    unsigned short* WaT  = (unsigned short*)p;  p += 2 * TN * wmat * 2;
    unsigned short* WffT = (unsigned short*)p;  p += wmat * 2;
    unsigned short* WattT = (unsigned short*)p; p += 2 * 64 * 256 * 2;
    unsigned short* WmsgT = (unsigned short*)p; p += 2 * 64 * 256 * 2;

    // weight conversion (once per launch): 65 matrices in one kernel
    wconv_all_kernel<<<65 * 8, 256, 0, stream>>>(Wk, Wq, Wv, Wa, Wff,
                                                 WkT, WqT, WvT, WaT, WffT);
    wsmall_conv<<<128, 256, 0, stream>>>(Watt, pri, WattT);     // pri/4 baked in
    wsmall_conv<<<128, 256, 0, stream>>>(Wmsg, nullptr, WmsgT);

    // node type sort (once)
    hipMemsetAsync(cnt, 0, TN * 4, stream);
    hipMemsetAsync(perm, 0xFF, (size_t)PERM_SZ * 4, stream);
    hist_kernel<<<(N_NODES + 255) / 256, 256, 0, stream>>>(ntype, cnt);
    scan_kernel<<<1, 64, 0, stream>>>(cnt, cursor);
    scatter_kernel<<<(N_NODES + 255) / 256, 256, 0, stream>>>(ntype, cursor, perm);

    // edge CSR by dst, then per-window relation tiles (once)
    hipMemsetAsync(cnt_dst, 0, (size_t)N_NODES * 4, stream);
    hist_dst_kernel<<<(N_EDGES + 255) / 256, 256, 0, stream>>>(dst, cnt_dst);
    scan_block_kernel<<<SCAN_BLKS, 256, 0, stream>>>(cnt_dst, row_ptr, bsum);
    scan_top_kernel<<<1, 256, 0, stream>>>(bsum);
    scan_add_kernel<<<SCAN_BLKS, 256, 0, stream>>>(row_ptr, bsum, cur_dst);
    csr_scatter_kernel<<<(N_EDGES + 255) / 256, 256, 0, stream>>>(src, dst, etype, cur_dst,
                                                                  csr_sd, csr_et);
    btile_build<<<NB, 64, 0, stream>>>(row_ptr, csr_sd, csr_et,
                                       btile_sd, btile_lp, btile_r, ntb);

    for (int l = 0; l < 2; ++l) {
        const float* xin = l ? embA : x;
        float* xout = l ? l1out : embA;
        const float* skip_l = skip + (size_t)l * TN;
        const float* g_l    = ln_g + (size_t)l * HID;
        const float* b_l    = ln_b + (size_t)l * HID;
        const unsigned short* WkT_l = WkT + (size_t)l * TN * wmat;
        const unsigned short* WqT_l = WqT + (size_t)l * TN * wmat;
        const unsigned short* WvT_l = WvT + (size_t)l * TN * wmat;
        const unsigned short* WaT_l = WaT + (size_t)l * TN * wmat;
        const unsigned short* WattT_l = WattT + (size_t)l * 64 * 256;
        const unsigned short* WmsgT_l = WmsgT + (size_t)l * 64 * 256;

        gemm3_mfma<<<MAXTILES, 256, 0, stream>>>(xin, perm, ntype, WkT_l, WqT_l, WvT_l,
                                                 Kbf, Qbf, Vbf);
        fused_attn_kernel<<<NB, 512, 0, stream>>>(Kbf, Vbf, Qbf, row_ptr, cnt_dst,
                                                  btile_sd, btile_lp, btile_r, ntb,
                                                  WattT_l, WmsgT_l, AGGb);
        // Wa typed GEMM + SiLU + gated residual + LayerNorm (fused, bf16 agg in)
        gemm1_ln_mfma<<<MAXTILES, 256, 0, stream>>>(AGGb, perm, ntype, WaT_l, xin,
                                                    skip_l, g_l, b_l, xout);
    }
    // final FF: l1out @ Wff + bff -> d_out
    gemm1_mfma<<<(N_NODES + TILE - 1) / TILE, 256, 0, stream>>>(l1out, nullptr, ntype, WffT,
                                                                bff, (float*)d_out);
}

// Round 20
// 411.416 us; speedup vs baseline: 1.0969x; 1.0197x over previous
//
#include <hip/hip_runtime.h>
#include <hip/hip_bf16.h>
#include <math.h>

#define N_NODES 50000
#define N_EDGES 400000
#define HID 128
#define NH 8
#define HS 16
#define TN 8
#define NR 8
#define TILE 32
#define MAXTILES 1571
#define PERM_SZ (MAXTILES * TILE)
#define SCAN_BLKS ((N_NODES + 255) / 256)   // 196
#define NB 3125                              // dst windows of 16 nodes (exact)
#define TPBMAX 26                            // max 16-edge tiles per window
#define CAP 240                              // max edges per window (~10 sigma)
#define MPITCH 68                            // smg row pitch in shorts
#define SPITCH 5                             // ssc row pitch in floats

typedef __attribute__((ext_vector_type(8))) short bf16x8;
typedef __attribute__((ext_vector_type(4))) float f32x4;

__device__ __forceinline__ unsigned short f2bf(float f) {
    __hip_bfloat16 h = __float2bfloat16(f);
    return *reinterpret_cast<unsigned short*>(&h);
}
__device__ __forceinline__ float bf2f(unsigned short u) {
    return __uint_as_float((unsigned)u << 16);
}

// ---------- node type sort (LDS-aggregated counting sort) ----------
__global__ void hist_kernel(const int* __restrict__ ntype, int* __restrict__ cnt) {
    __shared__ int l[TN];
    if (threadIdx.x < TN) l[threadIdx.x] = 0;
    __syncthreads();
    int i = blockIdx.x * 256 + threadIdx.x;
    if (i < N_NODES) atomicAdd(&l[ntype[i]], 1);
    __syncthreads();
    if (threadIdx.x < TN) atomicAdd(&cnt[threadIdx.x], l[threadIdx.x]);
}
__global__ void scan_kernel(const int* __restrict__ cnt, int* __restrict__ cursor) {
    if (threadIdx.x == 0 && blockIdx.x == 0) {
        int acc = 0;
        for (int t = 0; t < TN; ++t) {
            cursor[t] = acc;
            acc += ((cnt[t] + TILE - 1) / TILE) * TILE;
        }
    }
}
__global__ void scatter_kernel(const int* __restrict__ ntype, int* __restrict__ cursor,
                               int* __restrict__ perm) {
    __shared__ int lcnt[TN], lbase[TN];
    if (threadIdx.x < TN) lcnt[threadIdx.x] = 0;
    __syncthreads();
    int i = blockIdx.x * 256 + threadIdx.x;
    int t = 0, off = 0;
    if (i < N_NODES) {
        t = ntype[i];
        off = atomicAdd(&lcnt[t], 1);
    }
    __syncthreads();
    if (threadIdx.x < TN)
        lbase[threadIdx.x] = atomicAdd(&cursor[threadIdx.x], lcnt[threadIdx.x]);
    __syncthreads();
    if (i < N_NODES) perm[lbase[t] + off] = i;
}

// ---------- edge CSR build (sort by dst) ----------
__global__ void hist_dst_kernel(const int* __restrict__ dst, int* __restrict__ cnt) {
    int e = blockIdx.x * 256 + threadIdx.x;
    if (e < N_EDGES) atomicAdd(&cnt[dst[e]], 1);
}
__global__ void scan_block_kernel(const int* __restrict__ cnt, int* __restrict__ excl,
                                  int* __restrict__ bsum) {
    __shared__ int s[256];
    int tid = threadIdx.x;
    int i = blockIdx.x * 256 + tid;
    int v = (i < N_NODES) ? cnt[i] : 0;
    s[tid] = v;
    __syncthreads();
    for (int off = 1; off < 256; off <<= 1) {
        int t = (tid >= off) ? s[tid - off] : 0;
        __syncthreads();
        s[tid] += t;
        __syncthreads();
    }
    if (i < N_NODES) excl[i] = s[tid] - v;
    if (tid == 255) bsum[blockIdx.x] = s[255];
}
__global__ void scan_top_kernel(int* __restrict__ bsum) {
    __shared__ int s[256];
    int tid = threadIdx.x;
    int v = (tid < SCAN_BLKS) ? bsum[tid] : 0;
    s[tid] = v;
    __syncthreads();
    for (int off = 1; off < 256; off <<= 1) {
        int t = (tid >= off) ? s[tid - off] : 0;
        __syncthreads();
        s[tid] += t;
        __syncthreads();
    }
    if (tid < SCAN_BLKS) bsum[tid] = s[tid] - v;   // exclusive
}
__global__ void scan_add_kernel(int* __restrict__ excl, const int* __restrict__ bsum,
                                int* __restrict__ cursor) {
    int i = blockIdx.x * 256 + threadIdx.x;
    if (i < N_NODES) {
        int v = excl[i] + bsum[blockIdx.x];
        excl[i] = v;        // becomes row_ptr
        cursor[i] = v;
    }
}
// place edges at CSR positions (by dst)
__global__ void csr_scatter_kernel(const int* __restrict__ src, const int* __restrict__ dst,
                                   const int* __restrict__ etype, int* __restrict__ cur_dst,
                                   int* __restrict__ csr_sd, int* __restrict__ csr_et) {
    int e = blockIdx.x * 256 + threadIdx.x;
    if (e < N_EDGES) {
        int p = atomicAdd(&cur_dst[dst[e]], 1);
        csr_sd[p] = src[e] | (dst[e] << 16);
        csr_et[p] = etype[e];
    }
}

// ---------- per-window relation tile build (once) ----------
__global__ void btile_build(const int* __restrict__ row_ptr,
                            const int* __restrict__ csr_sd, const int* __restrict__ csr_et,
                            int* __restrict__ btile_sd, int* __restrict__ btile_lp,
                            int* __restrict__ btile_r, int* __restrict__ ntb) {
    int b = blockIdx.x;
    int lane = threadIdx.x;              // 64 threads = 1 wave
    int p0 = row_ptr[b * 16];
    int p1 = (b == NB - 1) ? N_EDGES : row_ptr[b * 16 + 16];
    int cnt = 0;
    if (lane < 8) {
        for (int p = p0; p < p1; ++p) cnt += (csr_et[p] == lane);
    }
    int tiles = (cnt + 15) >> 4;
    int pre = 0, total = 0;
    for (int k = 0; k < 8; ++k) {
        int tk = __shfl(tiles, k);
        if (k < lane) pre += tk;
        total += tk;
    }
    if (lane == 0) ntb[b] = total;
    if (lane < 8) {
        int tbase = b * TPBMAX + pre;
        for (int t = 0; t < tiles; ++t) btile_r[tbase + t] = lane;
        int off = 0;
        for (int p = p0; p < p1; ++p) {
            if (csr_et[p] == lane) {
                int idx = (tbase + (off >> 4)) * 16 + (off & 15);
                btile_sd[idx] = csr_sd[p];
                btile_lp[idx] = p - p0;
                ++off;
            }
        }
        for (; off < tiles * 16; ++off) {
            int idx = (tbase + (off >> 4)) * 16 + (off & 15);
            btile_sd[idx] = 0;
            btile_lp[idx] = CAP;         // scratch slot
        }
    }
}

// ---------- weight converts ----------
__global__ void wconv_all_kernel(const float* __restrict__ Wk, const float* __restrict__ Wq,
                                 const float* __restrict__ Wv, const float* __restrict__ Wa,
                                 const float* __restrict__ Wff,
                                 unsigned short* __restrict__ WkT, unsigned short* __restrict__ WqT,
                                 unsigned short* __restrict__ WvT, unsigned short* __restrict__ WaT,
                                 unsigned short* __restrict__ WffT) {
    int blk = blockIdx.x;                 // [0, 65*8)
    int m16 = blk >> 3;                   // 0..64 ; 64 => Wff
    int seg = blk & 7;
    const float* w;
    unsigned short* o;
    if (m16 < 64) {
        int grp = m16 >> 4, mat = m16 & 15;
        const float* Wsrc = grp == 0 ? Wk : (grp == 1 ? Wq : (grp == 2 ? Wv : Wa));
        unsigned short* Wdst = grp == 0 ? WkT : (grp == 1 ? WqT : (grp == 2 ? WvT : WaT));
        w = Wsrc + (size_t)mat * HID * HID;
        o = Wdst + (size_t)mat * HID * HID;
    } else {
        w = Wff;
        o = WffT;
    }
#pragma unroll
    for (int c = 0; c < 8; ++c) {
        int idx = seg * 2048 + c * 256 + threadIdx.x;
        int i = idx >> 7, j = idx & 127;
        o[j * HID + i] = f2bf(w[idx]);
    }
}
__global__ void wsmall_conv(const float* __restrict__ W, const float* __restrict__ pri,
                            unsigned short* __restrict__ out) {
    int blk = blockIdx.x;                 // l*64 + h*8 + r
    int tid = threadIdx.x;                // 256 = 16x16
    int i = tid >> 4, o = tid & 15;
    float s = pri ? pri[blk] * 0.25f : 1.f;
    out[blk * 256 + o * 16 + i] = f2bf(W[blk * 256 + i * 16 + o] * s);
}

// ---------- MFMA typed GEMM: 32 nodes x 128 outs; K,Q,V all bf16 ----------
__global__ __launch_bounds__(256) void gemm3_mfma(
    const float* __restrict__ x, const int* __restrict__ perm, const int* __restrict__ ntype,
    const unsigned short* __restrict__ WkT, const unsigned short* __restrict__ WqT,
    const unsigned short* __restrict__ WvT,
    unsigned short* __restrict__ Kb, unsigned short* __restrict__ Qb,
    unsigned short* __restrict__ Vb) {
    __shared__ unsigned short xs[TILE][HID + 8];
    __shared__ int nodes[TILE];
    int tid = threadIdx.x;
    if (tid < TILE) nodes[tid] = perm[blockIdx.x * TILE + tid];
    __syncthreads();
    if (nodes[0] < 0) return;
    int t = ntype[nodes[0]];
#pragma unroll
    for (int c = 0; c < 4; ++c) {
        int v = tid + c * 256;
        int ns = v >> 5, ii = (v & 31) * 4;
        int node = nodes[ns];
        float4 val = (node >= 0) ? *(const float4*)(x + (size_t)node * HID + ii)
                                 : make_float4(0.f, 0.f, 0.f, 0.f);
        uint2 pk;
        pk.x = (unsigned)f2bf(val.x) | ((unsigned)f2bf(val.y) << 16);
        pk.y = (unsigned)f2bf(val.z) | ((unsigned)f2bf(val.w) << 16);
        *(uint2*)&xs[ns][ii] = pk;
    }
    __syncthreads();
    int wv = tid >> 6, lane = tid & 63;
    int lrow = lane & 15, lk = lane >> 4;
    bf16x8 af[2][4];
#pragma unroll
    for (int rt = 0; rt < 2; ++rt)
#pragma unroll
        for (int kk = 0; kk < 4; ++kk)
            af[rt][kk] = *(const bf16x8*)&xs[rt * 16 + lrow][kk * 32 + lk * 8];
    size_t woff = (size_t)t * HID * HID + (size_t)lrow * HID + lk * 8;
#pragma unroll
    for (int pp = 0; pp < 6; ++pp) {
        int p = wv * 6 + pp;
        int mat = p >> 3, ct = p & 7;
        const unsigned short* wb =
            (mat == 0 ? WkT : (mat == 1 ? WqT : WvT)) + woff + (size_t)ct * 16 * HID;
        unsigned short* ob = (mat == 0) ? Kb : (mat == 1 ? Qb : Vb);
        f32x4 a0 = {0.f, 0.f, 0.f, 0.f}, a1 = {0.f, 0.f, 0.f, 0.f};
#pragma unroll
        for (int kk = 0; kk < 4; ++kk) {
            bf16x8 bfr = *(const bf16x8*)(wb + kk * 32);
            a0 = __builtin_amdgcn_mfma_f32_16x16x32_bf16(af[0][kk], bfr, a0, 0, 0, 0);
            a1 = __builtin_amdgcn_mfma_f32_16x16x32_bf16(af[1][kk], bfr, a1, 0, 0, 0);
        }
        int col = ct * 16 + lrow;
#pragma unroll
        for (int q = 0; q < 4; ++q) {
            int r0 = lk * 4 + q;
            int n0 = nodes[r0], n1 = nodes[16 + r0];
            if (n0 >= 0) ob[(size_t)n0 * HID + col] = f2bf(a0[q]);
            if (n1 >= 0) ob[(size_t)n1 * HID + col] = f2bf(a1[q]);
        }
    }
}

// ---------- MFMA GEMM (plain, fp32 in, fp32 out, +bias) for final FF ----------
__global__ __launch_bounds__(256) void gemm1_mfma(
    const float* __restrict__ x, const int* __restrict__ perm, const int* __restrict__ ntype,
    const unsigned short* __restrict__ Wt, const float* __restrict__ bias,
    float* __restrict__ out) {
    __shared__ unsigned short xs[TILE][HID + 8];
    __shared__ int nodes[TILE];
    int tid = threadIdx.x;
    if (tid < TILE) {
        int n;
        if (perm) n = perm[blockIdx.x * TILE + tid];
        else { n = blockIdx.x * TILE + tid; if (n >= N_NODES) n = -1; }
        nodes[tid] = n;
    }
    __syncthreads();
    if (nodes[0] < 0) return;
    int t = perm ? ntype[nodes[0]] : 0;
#pragma unroll
    for (int c = 0; c < 4; ++c) {
        int v = tid + c * 256;
        int ns = v >> 5, ii = (v & 31) * 4;
        int node = nodes[ns];
        float4 val = (node >= 0) ? *(const float4*)(x + (size_t)node * HID + ii)
                                 : make_float4(0.f, 0.f, 0.f, 0.f);
        uint2 pk;
        pk.x = (unsigned)f2bf(val.x) | ((unsigned)f2bf(val.y) << 16);
        pk.y = (unsigned)f2bf(val.z) | ((unsigned)f2bf(val.w) << 16);
        *(uint2*)&xs[ns][ii] = pk;
    }
    __syncthreads();
    int wv = tid >> 6, lane = tid & 63;
    int lrow = lane & 15, lk = lane >> 4;
    bf16x8 af[2][4];
#pragma unroll
    for (int rt = 0; rt < 2; ++rt)
#pragma unroll
        for (int kk = 0; kk < 4; ++kk)
            af[rt][kk] = *(const bf16x8*)&xs[rt * 16 + lrow][kk * 32 + lk * 8];
    const unsigned short* wb0 = Wt + (size_t)t * HID * HID + (size_t)lrow * HID + lk * 8;
#pragma unroll
    for (int pp = 0; pp < 2; ++pp) {
        int ct = wv * 2 + pp;
        const unsigned short* wb = wb0 + (size_t)ct * 16 * HID;
        f32x4 a0 = {0.f, 0.f, 0.f, 0.f}, a1 = {0.f, 0.f, 0.f, 0.f};
#pragma unroll
        for (int kk = 0; kk < 4; ++kk) {
            bf16x8 bfr = *(const bf16x8*)(wb + kk * 32);
            a0 = __builtin_amdgcn_mfma_f32_16x16x32_bf16(af[0][kk], bfr, a0, 0, 0, 0);
            a1 = __builtin_amdgcn_mfma_f32_16x16x32_bf16(af[1][kk], bfr, a1, 0, 0, 0);
        }
        float bv = bias ? bias[ct * 16 + lrow] : 0.f;
#pragma unroll
        for (int q = 0; q < 4; ++q) {
            int r0 = lk * 4 + q;
            int n0 = nodes[r0], n1 = nodes[16 + r0];
            if (n0 >= 0) out[(size_t)n0 * HID + ct * 16 + lrow] = a0[q] + bv;
            if (n1 >= 0) out[(size_t)n1 * HID + ct * 16 + lrow] = a1[q] + bv;
        }
    }
}

// ---------- MFMA typed GEMM (bf16 agg in) + SiLU + gated residual + LayerNorm ----------
__global__ __launch_bounds__(256) void gemm1_ln_mfma(
    const unsigned short* __restrict__ aggb, const int* __restrict__ perm,
    const int* __restrict__ ntype, const unsigned short* __restrict__ Wt,
    const float* __restrict__ xin, const float* __restrict__ skip,
    const float* __restrict__ g, const float* __restrict__ b, float* __restrict__ xout) {
    __shared__ unsigned short xs[TILE][HID + 8];
    __shared__ int nodes[TILE];
    __shared__ float psum[TILE][4], psq[TILE][4];
    __shared__ float mu_s[TILE], rv_s[TILE];
    int tid = threadIdx.x;
    if (tid < TILE) nodes[tid] = perm[blockIdx.x * TILE + tid];
    __syncthreads();
    if (nodes[0] < 0) return;
    int t = ntype[nodes[0]];
#pragma unroll
    for (int c = 0; c < 4; ++c) {
        int v = tid + c * 256;
        int ns = v >> 5, ii = (v & 31) * 4;
        int node = nodes[ns];
        uint2 pk = make_uint2(0u, 0u);
        if (node >= 0) pk = *(const uint2*)(aggb + (size_t)node * HID + ii);
        *(uint2*)&xs[ns][ii] = pk;
    }
    __syncthreads();
    int wv = tid >> 6, lane = tid & 63;
    int lrow = lane & 15, lk = lane >> 4;
    bf16x8 af[2][4];
#pragma unroll
    for (int rt = 0; rt < 2; ++rt)
#pragma unroll
        for (int kk = 0; kk < 4; ++kk)
            af[rt][kk] = *(const bf16x8*)&xs[rt * 16 + lrow][kk * 32 + lk * 8];
    const unsigned short* wb0 = Wt + (size_t)t * HID * HID + (size_t)lrow * HID + lk * 8;
    float al = 1.f / (1.f + __expf(-skip[t]));
    float om = 1.f - al;
    float ov[2][2][4];   // [pp][half][q]
#pragma unroll
    for (int pp = 0; pp < 2; ++pp) {
        int ct = wv * 2 + pp;
        const unsigned short* wb = wb0 + (size_t)ct * 16 * HID;
        f32x4 a0 = {0.f, 0.f, 0.f, 0.f}, a1 = {0.f, 0.f, 0.f, 0.f};
#pragma unroll
        for (int kk = 0; kk < 4; ++kk) {
            bf16x8 bfr = *(const bf16x8*)(wb + kk * 32);
            a0 = __builtin_amdgcn_mfma_f32_16x16x32_bf16(af[0][kk], bfr, a0, 0, 0, 0);
            a1 = __builtin_amdgcn_mfma_f32_16x16x32_bf16(af[1][kk], bfr, a1, 0, 0, 0);
        }
        int col = ct * 16 + lrow;
#pragma unroll
        for (int q = 0; q < 4; ++q) {
            int n0 = nodes[lk * 4 + q], n1 = nodes[16 + lk * 4 + q];
            float s0 = a0[q] / (1.f + __expf(-a0[q]));
            float s1 = a1[q] / (1.f + __expf(-a1[q]));
            float x0 = (n0 >= 0) ? xin[(size_t)n0 * HID + col] : 0.f;
            float x1 = (n1 >= 0) ? xin[(size_t)n1 * HID + col] : 0.f;
            ov[pp][0][q] = s0 * al + x0 * om;
            ov[pp][1][q] = s1 * al + x1 * om;
        }
    }
#pragma unroll
    for (int half = 0; half < 2; ++half)
#pragma unroll
        for (int q = 0; q < 4; ++q) {
            float s = ov[0][half][q] + ov[1][half][q];
            float s2 = ov[0][half][q] * ov[0][half][q] + ov[1][half][q] * ov[1][half][q];
            s += __shfl_xor(s, 1); s += __shfl_xor(s, 2);
            s += __shfl_xor(s, 4); s += __shfl_xor(s, 8);
            s2 += __shfl_xor(s2, 1); s2 += __shfl_xor(s2, 2);
            s2 += __shfl_xor(s2, 4); s2 += __shfl_xor(s2, 8);
            if (lrow == 0) {
                int nd = half * 16 + lk * 4 + q;
                psum[nd][wv] = s;
                psq[nd][wv] = s2;
            }
        }
    __syncthreads();
    if (tid < TILE) {
        float s = psum[tid][0] + psum[tid][1] + psum[tid][2] + psum[tid][3];
        float s2 = psq[tid][0] + psq[tid][1] + psq[tid][2] + psq[tid][3];
        float mu = s * (1.f / HID);
        float var = s2 * (1.f / HID) - mu * mu;
        mu_s[tid] = mu;
        rv_s[tid] = rsqrtf(fmaxf(var, 0.f) + 1e-5f);
    }
    __syncthreads();
#pragma unroll
    for (int pp = 0; pp < 2; ++pp) {
        int col = (wv * 2 + pp) * 16 + lrow;
        float gg = g[col], bb = b[col];
#pragma unroll
        for (int q = 0; q < 4; ++q) {
            int i0 = lk * 4 + q, i1 = 16 + lk * 4 + q;
            int n0 = nodes[i0], n1 = nodes[i1];
            if (n0 >= 0) xout[(size_t)n0 * HID + col] = (ov[pp][0][q] - mu_s[i0]) * rv_s[i0] * gg + bb;
            if (n1 >= 0) xout[(size_t)n1 * HID + col] = (ov[pp][1][q] - mu_s[i1]) * rv_s[i1] * gg + bb;
        }
    }
}

// ---------- fused attention: block = (dst window, 4-head pass) ----------
// r18 inner structure; the two 4-head passes now run as INDEPENDENT blocks.
__global__ __launch_bounds__(512) void fused_attn_kernel(
    const unsigned short* __restrict__ Kb, const unsigned short* __restrict__ Vb,
    const unsigned short* __restrict__ Qb,
    const int* __restrict__ row_ptr, const int* __restrict__ deg,
    const int* __restrict__ btile_sd, const int* __restrict__ btile_lp,
    const int* __restrict__ btile_r, const int* __restrict__ ntb,
    const unsigned short* __restrict__ WattT, const unsigned short* __restrict__ WmsgT,
    unsigned short* __restrict__ aggb) {
    __shared__ unsigned short smg[CAP + 1][MPITCH];
    __shared__ float ssc[CAP + 1][SPITCH];
    int b = blockIdx.x >> 1;
    int hbase = (blockIdx.x & 1) * 4;
    int wv = threadIdx.x >> 6, lane = threadIdx.x & 63;
    int ecol = lane & 15, lk = lane >> 4;
    int nt = ntb[b];
    int p0 = row_ptr[b * 16];
    const bf16x8 zz = {0, 0, 0, 0, 0, 0, 0, 0};

    // ---- phase 1: relation tiles -> LDS scores/mg ----
    for (int t = wv; t < nt; t += 8) {
        int ti = b * TPBMAX + t;
        int r = btile_r[ti];
        int sd = btile_sd[ti * 16 + ecol];
        int lp = btile_lp[ti * 16 + ecol];
        int s = sd & 0xFFFF, dd = ((unsigned)sd >> 16);
#pragma unroll
        for (int hh = 0; hh < 4; ++hh) {
            int h = hbase + hh;
            bf16x8 bk = zz, bv = zz, aa = zz, am = zz;
            if (lk < 2) {
                bk = *(const bf16x8*)(Kb + (size_t)s * HID + h * HS + lk * 8);
                bv = *(const bf16x8*)(Vb + (size_t)s * HID + h * HS + lk * 8);
                int wo = ((h * NR + r) * 16 + ecol) * 16 + lk * 8;
                aa = *(const bf16x8*)(WattT + wo);
                am = *(const bf16x8*)(WmsgT + wo);
            }
            f32x4 ck = {0.f, 0.f, 0.f, 0.f}, cm = {0.f, 0.f, 0.f, 0.f};
            ck = __builtin_amdgcn_mfma_f32_16x16x32_bf16(aa, bk, ck, 0, 0, 0);
            cm = __builtin_amdgcn_mfma_f32_16x16x32_bf16(am, bv, cm, 0, 0, 0);
            uint2 qraw = *(const uint2*)(Qb + (size_t)dd * HID + h * HS + lk * 4);
            float q0 = __uint_as_float(qraw.x << 16);
            float q1 = __uint_as_float(qraw.x & 0xffff0000u);
            float q2 = __uint_as_float(qraw.y << 16);
            float q3 = __uint_as_float(qraw.y & 0xffff0000u);
            float xsc = ck[0] * q0 + ck[1] * q1 + ck[2] * q2 + ck[3] * q3;
            xsc += __shfl_xor(xsc, 16);
            xsc += __shfl_xor(xsc, 32);
            if (lk == 0) ssc[lp][hh] = xsc;
            uint2 pk2;
            pk2.x = (unsigned)f2bf(cm[0]) | ((unsigned)f2bf(cm[1]) << 16);
            pk2.y = (unsigned)f2bf(cm[2]) | ((unsigned)f2bf(cm[3]) << 16);
            *(uint2*)&smg[lp][hh * 16 + lk * 4] = pk2;
        }
    }
    __syncthreads();
    // ---- phase 2: per-dst online softmax over LDS ----
    int h2 = lane >> 4, o = lane & 15;
#pragma unroll
    for (int i = 0; i < 2; ++i) {
        int d = b * 16 + wv * 2 + i;
        int lo = row_ptr[d] - p0;
        int dg = deg[d];
        float m = -INFINITY, den = 0.f, acc = 0.f;
        for (int e = 0; e < dg; ++e) {
            int lp = lo + e;
            float a = ssc[lp][h2];
            float gv = bf2f(smg[lp][h2 * 16 + o]);
            float mn = fmaxf(m, a);
            float scale = __expf(m - mn);
            float ex = __expf(a - mn);
            den = den * scale + ex;
            acc = acc * scale + ex * gv;
            m = mn;
        }
        aggb[(size_t)d * HID + (hbase + h2) * HS + o] = f2bf(acc / (den + 1e-16f));
    }
}

extern "C" void kernel_launch(void* const* d_in, const int* in_sizes, int n_in,
                              void* d_out, int out_size, void* d_ws, size_t ws_size,
                              hipStream_t stream) {
    const float* x     = (const float*)d_in[0];
    const int*   eidx  = (const int*)d_in[1];
    const int*   ntype = (const int*)d_in[2];
    const int*   etype = (const int*)d_in[3];
    const float* Wk    = (const float*)d_in[4];
    const float* Wq    = (const float*)d_in[5];
    const float* Wv    = (const float*)d_in[6];
    const float* Wa    = (const float*)d_in[7];
    const float* pri   = (const float*)d_in[8];
    const float* Watt  = (const float*)d_in[9];
    const float* Wmsg  = (const float*)d_in[10];
    const float* skip  = (const float*)d_in[11];
    const float* ln_g  = (const float*)d_in[12];
    const float* ln_b  = (const float*)d_in[13];
    const float* Wff   = (const float*)d_in[14];
    const float* bff   = (const float*)d_in[15];
    const int* src = eidx;
    const int* dst = eidx + N_EDGES;

    char* ws = (char*)d_ws;
    size_t szN = (size_t)N_NODES * HID * sizeof(float);        // 25.6 MB
    float* embA = (float*)(ws);                                // layer-0 out
    unsigned short* AGGb = (unsigned short*)(ws + szN);        // bf16 agg (12.8 MB)
    char*  kvq  = ws + 2 * szN;
    unsigned short* Kbf = (unsigned short*)kvq;                // 12.8 MB each
    unsigned short* Vbf = (unsigned short*)(kvq + (size_t)N_NODES * HID * 2);
    unsigned short* Qbf = (unsigned short*)(kvq + 2 * (size_t)N_NODES * HID * 2);
    float* l1out = (float*)kvq;                                // aliases K+V (dead by then)
    char*  p    = kvq + 3 * (size_t)N_NODES * HID * 2;
    int* perm    = (int*)p;  p += (size_t)PERM_SZ * 4;
    int* cnt     = (int*)p;  p += TN * 4;
    int* cursor  = (int*)p;  p += TN * 4;
    int* row_ptr = (int*)p;  p += (size_t)N_NODES * 4;
    int* cnt_dst = (int*)p;  p += (size_t)N_NODES * 4;
    int* cur_dst = (int*)p;  p += (size_t)N_NODES * 4;
    int* bsum    = (int*)p;  p += 256 * 4;
    int* csr_sd  = (int*)p;  p += (size_t)N_EDGES * 4;
    int* csr_et  = (int*)p;  p += (size_t)N_EDGES * 4;
    int* btile_sd = (int*)p; p += (size_t)NB * TPBMAX * 16 * 4;   // 5.2 MB
    int* btile_lp = (int*)p; p += (size_t)NB * TPBMAX * 16 * 4;   // 5.2 MB
    int* btile_r  = (int*)p; p += (size_t)NB * TPBMAX * 4;
    int* ntb      = (int*)p; p += (size_t)NB * 4;
    size_t wmat = (size_t)HID * HID;
    unsigned short* WkT  = (unsigned short*)p;  p += 2 * TN * wmat * 2;
    unsigned short* WqT  = (unsigned short*)p;  p += 2 * TN * wmat * 2;
    unsigned short* WvT  = (unsigned short*)p;  p += 2 * TN * wmat * 2;
    unsigned short* WaT  = (unsigned short*)p;  p += 2 * TN * wmat * 2;
    unsigned short* WffT = (unsigned short*)p;  p += wmat * 2;
    unsigned short* WattT = (unsigned short*)p; p += 2 * 64 * 256 * 2;
    unsigned short* WmsgT = (unsigned short*)p; p += 2 * 64 * 256 * 2;

    // weight conversion (once per launch): 65 matrices in one kernel
    wconv_all_kernel<<<65 * 8, 256, 0, stream>>>(Wk, Wq, Wv, Wa, Wff,
                                                 WkT, WqT, WvT, WaT, WffT);
    wsmall_conv<<<128, 256, 0, stream>>>(Watt, pri, WattT);     // pri/4 baked in
    wsmall_conv<<<128, 256, 0, stream>>>(Wmsg, nullptr, WmsgT);

    // node type sort (once)
    hipMemsetAsync(cnt, 0, TN * 4, stream);
    hipMemsetAsync(perm, 0xFF, (size_t)PERM_SZ * 4, stream);
    hist_kernel<<<(N_NODES + 255) / 256, 256, 0, stream>>>(ntype, cnt);
    scan_kernel<<<1, 64, 0, stream>>>(cnt, cursor);
    scatter_kernel<<<(N_NODES + 255) / 256, 256, 0, stream>>>(ntype, cursor, perm);

    // edge CSR by dst, then per-window relation tiles (once)
    hipMemsetAsync(cnt_dst, 0, (size_t)N_NODES * 4, stream);
    hist_dst_kernel<<<(N_EDGES + 255) / 256, 256, 0, stream>>>(dst, cnt_dst);
    scan_block_kernel<<<SCAN_BLKS, 256, 0, stream>>>(cnt_dst, row_ptr, bsum);
    scan_top_kernel<<<1, 256, 0, stream>>>(bsum);
    scan_add_kernel<<<SCAN_BLKS, 256, 0, stream>>>(row_ptr, bsum, cur_dst);
    csr_scatter_kernel<<<(N_EDGES + 255) / 256, 256, 0, stream>>>(src, dst, etype, cur_dst,
                                                                  csr_sd, csr_et);
    btile_build<<<NB, 64, 0, stream>>>(row_ptr, csr_sd, csr_et,
                                       btile_sd, btile_lp, btile_r, ntb);

    for (int l = 0; l < 2; ++l) {
        const float* xin = l ? embA : x;
        float* xout = l ? l1out : embA;
        const float* skip_l = skip + (size_t)l * TN;
        const float* g_l    = ln_g + (size_t)l * HID;
        const float* b_l    = ln_b + (size_t)l * HID;
        const unsigned short* WkT_l = WkT + (size_t)l * TN * wmat;
        const unsigned short* WqT_l = WqT + (size_t)l * TN * wmat;
        const unsigned short* WvT_l = WvT + (size_t)l * TN * wmat;
        const unsigned short* WaT_l = WaT + (size_t)l * TN * wmat;
        const unsigned short* WattT_l = WattT + (size_t)l * 64 * 256;
        const unsigned short* WmsgT_l = WmsgT + (size_t)l * 64 * 256;

        gemm3_mfma<<<MAXTILES, 256, 0, stream>>>(xin, perm, ntype, WkT_l, WqT_l, WvT_l,
                                                 Kbf, Qbf, Vbf);
        fused_attn_kernel<<<NB * 2, 512, 0, stream>>>(Kbf, Vbf, Qbf, row_ptr, cnt_dst,
                                                      btile_sd, btile_lp, btile_r, ntb,
                                                      WattT_l, WmsgT_l, AGGb);
        // Wa typed GEMM + SiLU + gated residual + LayerNorm (fused, bf16 agg in)
        gemm1_ln_mfma<<<MAXTILES, 256, 0, stream>>>(AGGb, perm, ntype, WaT_l, xin,
                                                    skip_l, g_l, b_l, xout);
    }
    // final FF: l1out @ Wff + bff -> d_out
    gemm1_mfma<<<(N_NODES + TILE - 1) / TILE, 256, 0, stream>>>(l1out, nullptr, ntype, WffT,
                                                                bff, (float*)d_out);
}